// Round 1
// baseline (1405.190 us; speedup 1.0000x reference)
//
#include <hip/hip_runtime.h>
#include <hip/hip_bf16.h>

#define NROWS 8192
#define NDIM  1024
#define SIGMA_INV 10.0f

typedef __attribute__((ext_vector_type(8))) short short8;
typedef __attribute__((ext_vector_type(4))) float floatx4;

__device__ __forceinline__ unsigned short f2b(float f) {
  union { float f; unsigned int u; } v; v.f = f;
  unsigned int r = v.u + 0x7fffu + ((v.u >> 16) & 1u);
  return (unsigned short)(r >> 16);
}

// ---------------- Kernel 1: row L2-normalize, cast to bf16 ----------------
// xb = bf16(row / max(||row||, 1e-12)), vb = bf16(row)
__global__ __launch_bounds__(256) void k_norm(const float* __restrict__ emb,
                                              unsigned short* __restrict__ xb,
                                              unsigned short* __restrict__ vb) {
  __shared__ float red[4];
  __shared__ float s_rinv;
  const int row = blockIdx.x;
  const int t = threadIdx.x;
  const float4 v = reinterpret_cast<const float4*>(emb + (size_t)row * NDIM)[t];
  float ss = v.x * v.x + v.y * v.y + v.z * v.z + v.w * v.w;
#pragma unroll
  for (int off = 32; off > 0; off >>= 1) ss += __shfl_down(ss, off);
  if ((t & 63) == 0) red[t >> 6] = ss;
  __syncthreads();
  if (t == 0) {
    float tot = red[0] + red[1] + red[2] + red[3];
    s_rinv = 1.0f / fmaxf(sqrtf(tot), 1e-12f);
  }
  __syncthreads();
  const float rinv = s_rinv;
  ushort4 xo, vo;
  xo.x = f2b(v.x * rinv); xo.y = f2b(v.y * rinv);
  xo.z = f2b(v.z * rinv); xo.w = f2b(v.w * rinv);
  vo.x = f2b(v.x); vo.y = f2b(v.y); vo.z = f2b(v.z); vo.w = f2b(v.w);
  reinterpret_cast<ushort4*>(xb + (size_t)row * NDIM)[t] = xo;
  reinterpret_cast<ushort4*>(vb + (size_t)row * NDIM)[t] = vo;
}

// ---------------- Kernel 2: fused S -> P -> (P@V, rowsum) ----------------
// Block tile: 64 i-rows x 1024 j-chunk. Phase A computes P (bf16) into LDS,
// Phase B computes partial numerator P @ V and atomically accumulates.
constexpr int BM = 64;    // i rows per block
constexpr int JC = 1024;  // j columns per block (chunk)
constexpr int BK = 32;    // K-step (one 16x16x32 MFMA consumes 32)
constexpr int BN = 128;   // j sub-tile in phase A
constexpr int BD = 128;   // d tile in phase B

__global__ __launch_bounds__(256, 1) void k_main(const unsigned short* __restrict__ xb,
                                                 const unsigned short* __restrict__ vb,
                                                 float* __restrict__ lsum,
                                                 float* __restrict__ out) {
  __shared__ unsigned short Ps[BM][JC + 8];   // 129 KB, +8 pad: 4-bank row skew
  __shared__ unsigned short As[BM][BK + 8];   // 5 KB, pad kills 8-way conflict
  __shared__ unsigned short Bs[BN][BK + 8];   // 10 KB
  __shared__ unsigned short Vs[BK][BD];       // 8 KB
  const int tid = threadIdx.x;
  const int lane = tid & 63, w = tid >> 6;
  const int quad = lane >> 4, l15 = lane & 15;
  const int wi = w >> 1, wj = w & 1;          // 2x2 wave grid, wave tile 32x64
  const int it0 = blockIdx.x * BM;
  const int jc0 = blockIdx.y * JC;

  float rowsum[2][4];
#pragma unroll
  for (int a = 0; a < 2; ++a)
#pragma unroll
    for (int b = 0; b < 4; ++b) rowsum[a][b] = 0.f;

  // ---------------- Phase A: P tile (64 x 1024) ----------------
  for (int jt = 0; jt < JC / BN; ++jt) {
    floatx4 acc[2][4];
#pragma unroll
    for (int fm = 0; fm < 2; ++fm)
#pragma unroll
      for (int fn = 0; fn < 4; ++fn) acc[fm][fn] = {0.f, 0.f, 0.f, 0.f};

    for (int k0 = 0; k0 < NDIM; k0 += BK) {
      {  // stage A tile: 64 rows x 32 k (one uint4 = 8 bf16 per thread)
        const int r = tid >> 2, seg = tid & 3;
        *reinterpret_cast<uint4*>(&As[r][seg * 8]) =
            *reinterpret_cast<const uint4*>(xb + (size_t)(it0 + r) * NDIM + k0 + seg * 8);
      }
#pragma unroll
      for (int p = 0; p < 2; ++p) {  // stage B tile: 128 rows x 32 k
        const int idx = tid + p * 256;
        const int r = idx >> 2, seg = idx & 3;
        *reinterpret_cast<uint4*>(&Bs[r][seg * 8]) =
            *reinterpret_cast<const uint4*>(xb + (size_t)(jc0 + jt * BN + r) * NDIM + k0 + seg * 8);
      }
      __syncthreads();
      short8 af[2], bfv[4];
#pragma unroll
      for (int fm = 0; fm < 2; ++fm)
        af[fm] = *reinterpret_cast<const short8*>(&As[wi * 32 + fm * 16 + l15][quad * 8]);
#pragma unroll
      for (int fn = 0; fn < 4; ++fn)
        bfv[fn] = *reinterpret_cast<const short8*>(&Bs[wj * 64 + fn * 16 + l15][quad * 8]);
#pragma unroll
      for (int fm = 0; fm < 2; ++fm)
#pragma unroll
        for (int fn = 0; fn < 4; ++fn)
          acc[fm][fn] = __builtin_amdgcn_mfma_f32_16x16x32_bf16(af[fm], bfv[fn], acc[fm][fn], 0, 0, 0);
      __syncthreads();
    }
    // P = exp(10*S - 10); accumulate row sums; store bf16 P to LDS
#pragma unroll
    for (int fm = 0; fm < 2; ++fm)
#pragma unroll
      for (int reg = 0; reg < 4; ++reg) {
        const int r = wi * 32 + fm * 16 + quad * 4 + reg;
#pragma unroll
        for (int fn = 0; fn < 4; ++fn) {
          const float pv = __expf(acc[fm][fn][reg] * SIGMA_INV - SIGMA_INV);
          rowsum[fm][reg] += pv;
          Ps[r][jt * BN + wj * 64 + fn * 16 + l15] = f2b(pv);
        }
      }
  }

  // denominator partials -> global atomics (lanes within a quad share rows)
#pragma unroll
  for (int fm = 0; fm < 2; ++fm)
#pragma unroll
    for (int reg = 0; reg < 4; ++reg) {
      float s = rowsum[fm][reg];
#pragma unroll
      for (int m = 1; m < 16; m <<= 1) s += __shfl_xor(s, m);
      if (l15 == 0)
        unsafeAtomicAdd(&lsum[it0 + wi * 32 + fm * 16 + quad * 4 + reg], s);
    }

  // ---------------- Phase B: numerator partial = P @ V ----------------
  for (int dt = 0; dt < NDIM / BD; ++dt) {
    floatx4 acc[2][4];
#pragma unroll
    for (int fm = 0; fm < 2; ++fm)
#pragma unroll
      for (int fn = 0; fn < 4; ++fn) acc[fm][fn] = {0.f, 0.f, 0.f, 0.f};

    for (int k0 = 0; k0 < JC; k0 += BK) {
#pragma unroll
      for (int p = 0; p < 2; ++p) {  // stage V tile: 32 j x 128 d
        const int idx = tid + p * 256;
        const int r = idx >> 4, seg = idx & 15;
        *reinterpret_cast<uint4*>(&Vs[r][seg * 8]) =
            *reinterpret_cast<const uint4*>(vb + (size_t)(jc0 + k0 + r) * NDIM + dt * BD + seg * 8);
      }
      __syncthreads();
      short8 af[2];
#pragma unroll
      for (int fm = 0; fm < 2; ++fm)
        af[fm] = *reinterpret_cast<const short8*>(&Ps[wi * 32 + fm * 16 + l15][k0 + quad * 8]);
      short8 bv[4];
#pragma unroll
      for (int fn = 0; fn < 4; ++fn) {
#pragma unroll
        for (int jj = 0; jj < 8; ++jj)
          bv[fn][jj] = (short)Vs[quad * 8 + jj][wj * 64 + fn * 16 + l15];
      }
#pragma unroll
      for (int fm = 0; fm < 2; ++fm)
#pragma unroll
        for (int fn = 0; fn < 4; ++fn)
          acc[fm][fn] = __builtin_amdgcn_mfma_f32_16x16x32_bf16(af[fm], bv[fn], acc[fm][fn], 0, 0, 0);
      __syncthreads();
    }
#pragma unroll
    for (int fm = 0; fm < 2; ++fm)
#pragma unroll
      for (int fn = 0; fn < 4; ++fn)
#pragma unroll
        for (int reg = 0; reg < 4; ++reg) {
          const size_t o = (size_t)(it0 + wi * 32 + fm * 16 + quad * 4 + reg) * NDIM +
                           dt * BD + wj * 64 + fn * 16 + l15;
          unsafeAtomicAdd(&out[o], acc[fm][fn][reg]);
        }
  }
}

// ---------------- Kernel 3: divide numerator by denominator ----------------
__global__ __launch_bounds__(256) void k_div(float* __restrict__ out,
                                             const float* __restrict__ lsum) {
  const int idx = blockIdx.x * 256 + threadIdx.x;  // float4 index
  float4 v = reinterpret_cast<float4*>(out)[idx];
  const float inv = 1.0f / lsum[idx >> 8];  // 256 float4 per row
  v.x *= inv; v.y *= inv; v.z *= inv; v.w *= inv;
  reinterpret_cast<float4*>(out)[idx] = v;
}

extern "C" void kernel_launch(void* const* d_in, const int* in_sizes, int n_in,
                              void* d_out, int out_size, void* d_ws, size_t ws_size,
                              hipStream_t stream) {
  const float* emb = (const float*)d_in[0];
  float* out = (float*)d_out;
  unsigned short* xb = (unsigned short*)d_ws;                     // 16 MB bf16 x
  unsigned short* vb = xb + (size_t)NROWS * NDIM;                 // 16 MB bf16 V
  float* lsum = (float*)(vb + (size_t)NROWS * NDIM);              // 32 KB denoms

  hipMemsetAsync(out, 0, (size_t)NROWS * NDIM * sizeof(float), stream);
  hipMemsetAsync(lsum, 0, NROWS * sizeof(float), stream);

  k_norm<<<NROWS, 256, 0, stream>>>(emb, xb, vb);
  k_main<<<dim3(NROWS / BM, NROWS / JC), 256, 0, stream>>>(xb, vb, lsum, out);
  k_div<<<(NROWS * NDIM / 4) / 256, 256, 0, stream>>>(out, lsum);
}

// Round 2
// 604.742 us; speedup vs baseline: 2.3236x; 2.3236x over previous
//
#include <hip/hip_runtime.h>
#include <hip/hip_bf16.h>

#define NROWS 8192
#define NDIM  1024

typedef __attribute__((ext_vector_type(8))) short short8;
typedef __attribute__((ext_vector_type(4))) float floatx4;

__device__ __forceinline__ unsigned short f2b(float f) {
  union { float f; unsigned int u; } v; v.f = f;
  unsigned int r = v.u + 0x7fffu + ((v.u >> 16) & 1u);
  return (unsigned short)(r >> 16);
}

// async global->LDS, 16B per lane. lds must be the wave-uniform base;
// HW writes lane's 16B at lds + lane*16.
__device__ __forceinline__ void async16(void* lds, const void* g) {
  __builtin_amdgcn_global_load_lds(
      (const __attribute__((address_space(1))) unsigned int*)g,
      (__attribute__((address_space(3))) unsigned int*)lds, 16, 0, 0);
}

// ---------------- Kernel 1: row L2-normalize -> bf16 x ----------------
__global__ __launch_bounds__(256) void k_norm(const float* __restrict__ emb,
                                              unsigned short* __restrict__ xb) {
  __shared__ float red[4];
  __shared__ float s_rinv;
  const int row = blockIdx.x;
  const int t = threadIdx.x;
  const float4 v = reinterpret_cast<const float4*>(emb + (size_t)row * NDIM)[t];
  float ss = v.x * v.x + v.y * v.y + v.z * v.z + v.w * v.w;
#pragma unroll
  for (int off = 32; off > 0; off >>= 1) ss += __shfl_down(ss, off);
  if ((t & 63) == 0) red[t >> 6] = ss;
  __syncthreads();
  if (t == 0) s_rinv = 1.0f / fmaxf(sqrtf(red[0] + red[1] + red[2] + red[3]), 1e-12f);
  __syncthreads();
  const float rinv = s_rinv;
  ushort4 xo;
  xo.x = f2b(v.x * rinv); xo.y = f2b(v.y * rinv);
  xo.z = f2b(v.z * rinv); xo.w = f2b(v.w * rinv);
  reinterpret_cast<ushort4*>(xb + (size_t)row * NDIM)[t] = xo;
}

// ---------------- Kernel 2: transpose emb -> Vt bf16 [NDIM][NROWS] ----------
__global__ __launch_bounds__(256) void k_tr(const float* __restrict__ emb,
                                            unsigned short* __restrict__ Vt) {
  __shared__ __align__(16) unsigned short T[64][80];  // +16 pad, rows 160B (16B-aligned)
  const int r0 = blockIdx.x * 64;  // source rows (N)
  const int c0 = blockIdx.y * 64;  // source cols (D)
  const int t = threadIdx.x;
#pragma unroll
  for (int p = 0; p < 4; ++p) {
    const int r = (t >> 4) + 16 * p;
    const int c = (t & 15) * 4;
    const float4 v = *reinterpret_cast<const float4*>(emb + (size_t)(r0 + r) * NDIM + c0 + c);
    T[c + 0][r] = f2b(v.x); T[c + 1][r] = f2b(v.y);
    T[c + 2][r] = f2b(v.z); T[c + 3][r] = f2b(v.w);
  }
  __syncthreads();
#pragma unroll
  for (int p = 0; p < 2; ++p) {
    const int d = (t >> 3) + 32 * p;
    const int seg = t & 7;
    const uint4 v = *reinterpret_cast<const uint4*>(&T[d][seg * 8]);
    *reinterpret_cast<uint4*>(Vt + (size_t)(c0 + d) * NROWS + r0 + seg * 8) = v;
  }
}

// ---------------- Kernel 3: S = x x^T, P = exp(10S-10), rowsums -----------
// m97 recipe: 128x128 tile, 4 waves (2x2), wave tile 64x64 = 4x4 frags of 16x16.
// LDS k-major: As[kseg 4][row 128][8 bf16], staged via global_load_lds width 16.
__global__ __launch_bounds__(256) void k_s(const unsigned short* __restrict__ xb,
                                           unsigned short* __restrict__ P,
                                           float* __restrict__ lsum,
                                           int ch0) {
  __shared__ __align__(16) unsigned short As[4 * 128 * 8];  // 8 KB
  __shared__ __align__(16) unsigned short Bs[4 * 128 * 8];  // 8 KB
  const int tid = threadIdx.x;
  const int lane = tid & 63, w = tid >> 6;
  const int quad = lane >> 4, l15 = lane & 15;
  const int wi = w >> 1, wj = w & 1;
  const int it0 = blockIdx.x * 128;  // chunk-local i tile
  const int jt0 = blockIdx.y * 128;

  floatx4 acc[4][4];
#pragma unroll
  for (int a = 0; a < 4; ++a)
#pragma unroll
    for (int b = 0; b < 4; ++b) acc[a][b] = {0.f, 0.f, 0.f, 0.f};

  const unsigned short* gA = xb + (size_t)(ch0 + it0 + lane) * NDIM + w * 8;
  const unsigned short* gB = xb + (size_t)(jt0 + lane) * NDIM + w * 8;
  unsigned short* lA = As + w * 1024;  // wave-uniform base (bytes: w*2048)
  unsigned short* lB = Bs + w * 1024;

  for (int k0 = 0; k0 < NDIM; k0 += 32) {
    async16(lA, gA);
    async16(lA + 512, gA + 64 * NDIM);
    async16(lB, gB);
    async16(lB + 512, gB + 64 * NDIM);
    gA += 32; gB += 32;
    __syncthreads();
    short8 af[4], bfr[4];
#pragma unroll
    for (int fm = 0; fm < 4; ++fm)
      af[fm] = *reinterpret_cast<const short8*>(As + quad * 1024 + (wi * 64 + fm * 16 + l15) * 8);
#pragma unroll
    for (int fn = 0; fn < 4; ++fn)
      bfr[fn] = *reinterpret_cast<const short8*>(Bs + quad * 1024 + (wj * 64 + fn * 16 + l15) * 8);
#pragma unroll
    for (int fm = 0; fm < 4; ++fm)
#pragma unroll
      for (int fn = 0; fn < 4; ++fn)
        acc[fm][fn] = __builtin_amdgcn_mfma_f32_16x16x32_bf16(af[fm], bfr[fn], acc[fm][fn], 0, 0, 0);
    __syncthreads();
  }

  // epilogue: P = exp(10*s - 10) (S_ii = 10/sigma is the exact row max), rowsums
#pragma unroll
  for (int fm = 0; fm < 4; ++fm)
#pragma unroll
    for (int reg = 0; reg < 4; ++reg) {
      const int row = wi * 64 + fm * 16 + quad * 4 + reg;
      float s = 0.f;
#pragma unroll
      for (int fn = 0; fn < 4; ++fn) {
        const float p = __expf(fmaf(acc[fm][fn][reg], 10.f, -10.f));
        s += p;
        P[(size_t)(it0 + row) * NROWS + jt0 + wj * 64 + fn * 16 + l15] = f2b(p);
      }
#pragma unroll
      for (int m = 1; m < 16; m <<= 1) s += __shfl_xor(s, m);
      if (l15 == 0) unsafeAtomicAdd(&lsum[ch0 + it0 + row], s);
    }
}

// ---------------- Kernel 4: out = (P @ V) / lsum  (B from Vt rows) --------
__global__ __launch_bounds__(256) void k_pv(const unsigned short* __restrict__ P,
                                            const unsigned short* __restrict__ Vt,
                                            const float* __restrict__ lsum,
                                            float* __restrict__ out,
                                            int ch0) {
  __shared__ __align__(16) unsigned short As[4 * 128 * 8];
  __shared__ __align__(16) unsigned short Bs[4 * 128 * 8];
  const int tid = threadIdx.x;
  const int lane = tid & 63, w = tid >> 6;
  const int quad = lane >> 4, l15 = lane & 15;
  const int wi = w >> 1, wj = w & 1;
  const int it0 = blockIdx.x * 128;  // chunk-local i tile
  const int dt0 = blockIdx.y * 128;  // d tile

  floatx4 acc[4][4];
#pragma unroll
  for (int a = 0; a < 4; ++a)
#pragma unroll
    for (int b = 0; b < 4; ++b) acc[a][b] = {0.f, 0.f, 0.f, 0.f};

  const unsigned short* gA = P + (size_t)(it0 + lane) * NROWS + w * 8;
  const unsigned short* gB = Vt + (size_t)(dt0 + lane) * NROWS + w * 8;
  unsigned short* lA = As + w * 1024;
  unsigned short* lB = Bs + w * 1024;

  for (int k0 = 0; k0 < NROWS; k0 += 32) {
    async16(lA, gA);
    async16(lA + 512, gA + 64 * NROWS);
    async16(lB, gB);
    async16(lB + 512, gB + 64 * NROWS);
    gA += 32; gB += 32;
    __syncthreads();
    short8 af[4], bfr[4];
#pragma unroll
    for (int fm = 0; fm < 4; ++fm)
      af[fm] = *reinterpret_cast<const short8*>(As + quad * 1024 + (wi * 64 + fm * 16 + l15) * 8);
#pragma unroll
    for (int fn = 0; fn < 4; ++fn)
      bfr[fn] = *reinterpret_cast<const short8*>(Bs + quad * 1024 + (wj * 64 + fn * 16 + l15) * 8);
#pragma unroll
    for (int fm = 0; fm < 4; ++fm)
#pragma unroll
      for (int fn = 0; fn < 4; ++fn)
        acc[fm][fn] = __builtin_amdgcn_mfma_f32_16x16x32_bf16(af[fm], bfr[fn], acc[fm][fn], 0, 0, 0);
    __syncthreads();
  }

#pragma unroll
  for (int fm = 0; fm < 4; ++fm)
#pragma unroll
    for (int reg = 0; reg < 4; ++reg) {
      const int row = wi * 64 + fm * 16 + quad * 4 + reg;
      const float rinv = 1.0f / lsum[ch0 + it0 + row];
#pragma unroll
      for (int fn = 0; fn < 4; ++fn)
        out[(size_t)(ch0 + it0 + row) * NDIM + dt0 + wj * 64 + fn * 16 + l15] =
            acc[fm][fn][reg] * rinv;
    }
}

extern "C" void kernel_launch(void* const* d_in, const int* in_sizes, int n_in,
                              void* d_out, int out_size, void* d_ws, size_t ws_size,
                              hipStream_t stream) {
  const float* emb = (const float*)d_in[0];
  float* out = (float*)d_out;

  unsigned short* xb = (unsigned short*)d_ws;                       // 16 MB
  unsigned short* Vt = xb + (size_t)NROWS * NDIM;                   // 16 MB
  float* lsum = (float*)(Vt + (size_t)NROWS * NDIM);                // 32 KB
  unsigned short* P = (unsigned short*)((char*)d_ws + (34ull << 20));  // rest

  // chunk the i-dimension if ws can't hold the full 134 MB P
  const size_t avail = ws_size > (34ull << 20) ? ws_size - (34ull << 20) : 0;
  int nc = 1;
  while (nc < 64 && ((size_t)(NROWS / nc) * NROWS * 2) > avail) nc <<= 1;
  const int RC = NROWS / nc;

  hipMemsetAsync(lsum, 0, NROWS * sizeof(float), stream);
  k_norm<<<NROWS, 256, 0, stream>>>(emb, xb);
  k_tr<<<dim3(NROWS / 64, NDIM / 64), 256, 0, stream>>>(emb, Vt);
  for (int c = 0; c < nc; ++c) {
    const int ch0 = c * RC;
    k_s<<<dim3(RC / 128, NROWS / 128), 256, 0, stream>>>(xb, P, lsum, ch0);
    k_pv<<<dim3(RC / 128, NDIM / 128), 256, 0, stream>>>(P, Vt, lsum, out, ch0);
  }
}

// Round 3
// 555.417 us; speedup vs baseline: 2.5300x; 1.0888x over previous
//
#include <hip/hip_runtime.h>
#include <hip/hip_bf16.h>

#define NROWS 8192
#define NDIM  1024

typedef __attribute__((ext_vector_type(8))) short short8;
typedef __attribute__((ext_vector_type(4))) float floatx4;

__device__ __forceinline__ unsigned short f2b(float f) {
  union { float f; unsigned int u; } v; v.f = f;
  unsigned int r = v.u + 0x7fffu + ((v.u >> 16) & 1u);
  return (unsigned short)(r >> 16);
}

__device__ __forceinline__ void async16(void* lds, const void* g) {
  __builtin_amdgcn_global_load_lds(
      (const __attribute__((address_space(1))) unsigned int*)g,
      (__attribute__((address_space(3))) unsigned int*)lds, 16, 0, 0);
}

// ---------------- Kernel 1: row L2-normalize -> bf16 x ----------------
__global__ __launch_bounds__(256) void k_norm(const float* __restrict__ emb,
                                              unsigned short* __restrict__ xb) {
  __shared__ float red[4];
  __shared__ float s_rinv;
  const int row = blockIdx.x;
  const int t = threadIdx.x;
  const float4 v = reinterpret_cast<const float4*>(emb + (size_t)row * NDIM)[t];
  float ss = v.x * v.x + v.y * v.y + v.z * v.z + v.w * v.w;
#pragma unroll
  for (int off = 32; off > 0; off >>= 1) ss += __shfl_down(ss, off);
  if ((t & 63) == 0) red[t >> 6] = ss;
  __syncthreads();
  if (t == 0) s_rinv = 1.0f / fmaxf(sqrtf(red[0] + red[1] + red[2] + red[3]), 1e-12f);
  __syncthreads();
  const float rinv = s_rinv;
  ushort4 xo;
  xo.x = f2b(v.x * rinv); xo.y = f2b(v.y * rinv);
  xo.z = f2b(v.z * rinv); xo.w = f2b(v.w * rinv);
  reinterpret_cast<ushort4*>(xb + (size_t)row * NDIM)[t] = xo;
}

// ---------------- Kernel 2: transpose emb -> Vt bf16 [NDIM][NROWS] ----------
__global__ __launch_bounds__(256) void k_tr(const float* __restrict__ emb,
                                            unsigned short* __restrict__ Vt) {
  __shared__ __align__(16) unsigned short T[64][80];
  const int r0 = blockIdx.x * 64;
  const int c0 = blockIdx.y * 64;
  const int t = threadIdx.x;
#pragma unroll
  for (int p = 0; p < 4; ++p) {
    const int r = (t >> 4) + 16 * p;
    const int c = (t & 15) * 4;
    const float4 v = *reinterpret_cast<const float4*>(emb + (size_t)(r0 + r) * NDIM + c0 + c);
    T[c + 0][r] = f2b(v.x); T[c + 1][r] = f2b(v.y);
    T[c + 2][r] = f2b(v.z); T[c + 3][r] = f2b(v.w);
  }
  __syncthreads();
#pragma unroll
  for (int p = 0; p < 2; ++p) {
    const int d = (t >> 3) + 32 * p;
    const int seg = t & 7;
    const uint4 v = *reinterpret_cast<const uint4*>(&T[d][seg * 8]);
    *reinterpret_cast<uint4*>(Vt + (size_t)(c0 + d) * NROWS + r0 + seg * 8) = v;
  }
}

// ---------------- Kernel 3a: symmetric S -> P, triangle grid ----------------
// 2080 blocks over upper-triangle tile pairs (bi<=bj). Off-diagonal blocks
// write P tile + transposed tile (P symmetric) and both row/col sums.
__global__ __launch_bounds__(256) void k_s_sym(const unsigned short* __restrict__ xb,
                                               unsigned short* __restrict__ P,
                                               float* __restrict__ lsum) {
  __shared__ __align__(16) unsigned short As[4 * 128 * 8];
  __shared__ __align__(16) unsigned short Bs[4 * 128 * 8];
  const int tid = threadIdx.x;
  const int lane = tid & 63, w = tid >> 6;
  const int quad = lane >> 4, l15 = lane & 15;
  const int wi = w >> 1, wj = w & 1;

  // decode triangle index: idx = bj*(bj+1)/2 + bi, bi <= bj
  const int idx = blockIdx.x;
  int bj = (int)((sqrtf(8.0f * idx + 1.0f) - 1.0f) * 0.5f);
  while ((bj + 1) * (bj + 2) / 2 <= idx) ++bj;
  while (bj * (bj + 1) / 2 > idx) --bj;
  const int bi = idx - bj * (bj + 1) / 2;
  const int it0 = bi * 128, jt0 = bj * 128;

  floatx4 acc[4][4];
#pragma unroll
  for (int a = 0; a < 4; ++a)
#pragma unroll
    for (int b = 0; b < 4; ++b) acc[a][b] = {0.f, 0.f, 0.f, 0.f};

  const unsigned short* gA = xb + (size_t)(it0 + lane) * NDIM + w * 8;
  const unsigned short* gB = xb + (size_t)(jt0 + lane) * NDIM + w * 8;
  unsigned short* lA = As + w * 1024;
  unsigned short* lB = Bs + w * 1024;

  for (int k0 = 0; k0 < NDIM; k0 += 32) {
    async16(lA, gA);
    async16(lA + 512, gA + 64 * NDIM);
    async16(lB, gB);
    async16(lB + 512, gB + 64 * NDIM);
    gA += 32; gB += 32;
    __syncthreads();
    short8 af[4], bfr[4];
#pragma unroll
    for (int fm = 0; fm < 4; ++fm)
      af[fm] = *reinterpret_cast<const short8*>(As + quad * 1024 + (wi * 64 + fm * 16 + l15) * 8);
#pragma unroll
    for (int fn = 0; fn < 4; ++fn)
      bfr[fn] = *reinterpret_cast<const short8*>(Bs + quad * 1024 + (wj * 64 + fn * 16 + l15) * 8);
#pragma unroll
    for (int fm = 0; fm < 4; ++fm)
#pragma unroll
      for (int fn = 0; fn < 4; ++fn)
        acc[fm][fn] = __builtin_amdgcn_mfma_f32_16x16x32_bf16(af[fm], bfr[fn], acc[fm][fn], 0, 0, 0);
    __syncthreads();
  }

  // P = exp(10*s - 10) in place
#pragma unroll
  for (int fm = 0; fm < 4; ++fm)
#pragma unroll
    for (int fn = 0; fn < 4; ++fn)
#pragma unroll
      for (int reg = 0; reg < 4; ++reg)
        acc[fm][fn][reg] = __expf(fmaf(acc[fm][fn][reg], 10.f, -10.f));

  // normal store + rowsums
#pragma unroll
  for (int fm = 0; fm < 4; ++fm)
#pragma unroll
    for (int reg = 0; reg < 4; ++reg) {
      const int row = wi * 64 + fm * 16 + quad * 4 + reg;
      float s = 0.f;
#pragma unroll
      for (int fn = 0; fn < 4; ++fn) {
        const float p = acc[fm][fn][reg];
        s += p;
        P[(size_t)(it0 + row) * NROWS + jt0 + wj * 64 + fn * 16 + l15] = f2b(p);
      }
#pragma unroll
      for (int m = 1; m < 16; m <<= 1) s += __shfl_xor(s, m);
      if (l15 == 0) unsafeAtomicAdd(&lsum[it0 + row], s);
    }

  if (bi != bj) {
    // transposed store (contiguous ushort4 in i) + colsums
#pragma unroll
    for (int fn = 0; fn < 4; ++fn) {
      const int col = wj * 64 + fn * 16 + l15;
      float cs = 0.f;
#pragma unroll
      for (int fm = 0; fm < 4; ++fm) {
        ushort4 t;
        t.x = f2b(acc[fm][fn][0]); t.y = f2b(acc[fm][fn][1]);
        t.z = f2b(acc[fm][fn][2]); t.w = f2b(acc[fm][fn][3]);
        cs += acc[fm][fn][0] + acc[fm][fn][1] + acc[fm][fn][2] + acc[fm][fn][3];
        *reinterpret_cast<ushort4*>(
            &P[(size_t)(jt0 + col) * NROWS + it0 + wi * 64 + fm * 16 + quad * 4]) = t;
      }
      cs += __shfl_xor(cs, 16);
      cs += __shfl_xor(cs, 32);
      if (quad == 0) unsafeAtomicAdd(&lsum[jt0 + col], cs);
    }
  }
}

// ---------------- Kernel 3b: full-grid S -> P (chunked fallback) ----------
__global__ __launch_bounds__(256) void k_s_full(const unsigned short* __restrict__ xb,
                                                unsigned short* __restrict__ P,
                                                float* __restrict__ lsum, int ch0) {
  __shared__ __align__(16) unsigned short As[4 * 128 * 8];
  __shared__ __align__(16) unsigned short Bs[4 * 128 * 8];
  const int tid = threadIdx.x;
  const int lane = tid & 63, w = tid >> 6;
  const int quad = lane >> 4, l15 = lane & 15;
  const int wi = w >> 1, wj = w & 1;
  const int it0 = blockIdx.x * 128;
  const int jt0 = blockIdx.y * 128;

  floatx4 acc[4][4];
#pragma unroll
  for (int a = 0; a < 4; ++a)
#pragma unroll
    for (int b = 0; b < 4; ++b) acc[a][b] = {0.f, 0.f, 0.f, 0.f};

  const unsigned short* gA = xb + (size_t)(ch0 + it0 + lane) * NDIM + w * 8;
  const unsigned short* gB = xb + (size_t)(jt0 + lane) * NDIM + w * 8;
  unsigned short* lA = As + w * 1024;
  unsigned short* lB = Bs + w * 1024;

  for (int k0 = 0; k0 < NDIM; k0 += 32) {
    async16(lA, gA);
    async16(lA + 512, gA + 64 * NDIM);
    async16(lB, gB);
    async16(lB + 512, gB + 64 * NDIM);
    gA += 32; gB += 32;
    __syncthreads();
    short8 af[4], bfr[4];
#pragma unroll
    for (int fm = 0; fm < 4; ++fm)
      af[fm] = *reinterpret_cast<const short8*>(As + quad * 1024 + (wi * 64 + fm * 16 + l15) * 8);
#pragma unroll
    for (int fn = 0; fn < 4; ++fn)
      bfr[fn] = *reinterpret_cast<const short8*>(Bs + quad * 1024 + (wj * 64 + fn * 16 + l15) * 8);
#pragma unroll
    for (int fm = 0; fm < 4; ++fm)
#pragma unroll
      for (int fn = 0; fn < 4; ++fn)
        acc[fm][fn] = __builtin_amdgcn_mfma_f32_16x16x32_bf16(af[fm], bfr[fn], acc[fm][fn], 0, 0, 0);
    __syncthreads();
  }

#pragma unroll
  for (int fm = 0; fm < 4; ++fm)
#pragma unroll
    for (int reg = 0; reg < 4; ++reg) {
      const int row = wi * 64 + fm * 16 + quad * 4 + reg;
      float s = 0.f;
#pragma unroll
      for (int fn = 0; fn < 4; ++fn) {
        const float p = __expf(fmaf(acc[fm][fn][reg], 10.f, -10.f));
        s += p;
        P[(size_t)(it0 + row) * NROWS + jt0 + wj * 64 + fn * 16 + l15] = f2b(p);
      }
#pragma unroll
      for (int m = 1; m < 16; m <<= 1) s += __shfl_xor(s, m);
      if (l15 == 0) unsafeAtomicAdd(&lsum[ch0 + it0 + row], s);
    }
}

// ------- Kernel 4: out^T = Vt @ P^T (P symmetric), /lsum, float4 stores -----
__global__ __launch_bounds__(256) void k_pvT(const unsigned short* __restrict__ P,
                                             const unsigned short* __restrict__ Vt,
                                             const float* __restrict__ lsum,
                                             float* __restrict__ out, int ch0) {
  __shared__ __align__(16) unsigned short As[4 * 128 * 8];
  __shared__ __align__(16) unsigned short Bs[4 * 128 * 8];
  const int tid = threadIdx.x;
  const int lane = tid & 63, w = tid >> 6;
  const int quad = lane >> 4, l15 = lane & 15;
  const int wi = w >> 1, wj = w & 1;
  const int dt0 = blockIdx.x * 128;  // d tile (M of out^T)
  const int it0 = blockIdx.y * 128;  // i tile (N of out^T), chunk-local

  floatx4 acc[4][4];
#pragma unroll
  for (int a = 0; a < 4; ++a)
#pragma unroll
    for (int b = 0; b < 4; ++b) acc[a][b] = {0.f, 0.f, 0.f, 0.f};

  const unsigned short* gA = Vt + (size_t)(dt0 + lane) * NROWS + w * 8;
  const unsigned short* gB = P + (size_t)(it0 + lane) * NROWS + w * 8;
  unsigned short* lA = As + w * 1024;
  unsigned short* lB = Bs + w * 1024;

  for (int k0 = 0; k0 < NROWS; k0 += 32) {
    async16(lA, gA);
    async16(lA + 512, gA + 64 * NROWS);
    async16(lB, gB);
    async16(lB + 512, gB + 64 * NROWS);
    gA += 32; gB += 32;
    __syncthreads();
    short8 af[4], bfr[4];
#pragma unroll
    for (int fm = 0; fm < 4; ++fm)
      af[fm] = *reinterpret_cast<const short8*>(As + quad * 1024 + (wi * 64 + fm * 16 + l15) * 8);
#pragma unroll
    for (int fn = 0; fn < 4; ++fn)
      bfr[fn] = *reinterpret_cast<const short8*>(Bs + quad * 1024 + (wj * 64 + fn * 16 + l15) * 8);
#pragma unroll
    for (int fm = 0; fm < 4; ++fm)
#pragma unroll
      for (int fn = 0; fn < 4; ++fn)
        acc[fm][fn] = __builtin_amdgcn_mfma_f32_16x16x32_bf16(af[fm], bfr[fn], acc[fm][fn], 0, 0, 0);
    __syncthreads();
  }

#pragma unroll
  for (int fn = 0; fn < 4; ++fn) {
    const int i = it0 + wj * 64 + fn * 16 + l15;
    const float rinv = 1.0f / lsum[ch0 + i];
#pragma unroll
    for (int fm = 0; fm < 4; ++fm) {
      const int d = dt0 + wi * 64 + fm * 16 + quad * 4;
      float4 o;
      o.x = acc[fm][fn][0] * rinv; o.y = acc[fm][fn][1] * rinv;
      o.z = acc[fm][fn][2] * rinv; o.w = acc[fm][fn][3] * rinv;
      *reinterpret_cast<float4*>(&out[(size_t)(ch0 + i) * NDIM + d]) = o;
    }
  }
}

extern "C" void kernel_launch(void* const* d_in, const int* in_sizes, int n_in,
                              void* d_out, int out_size, void* d_ws, size_t ws_size,
                              hipStream_t stream) {
  const float* emb = (const float*)d_in[0];
  float* out = (float*)d_out;

  unsigned short* xb = (unsigned short*)d_ws;                          // 16 MB
  unsigned short* Vt = xb + (size_t)NROWS * NDIM;                      // 16 MB
  float* lsum = (float*)(Vt + (size_t)NROWS * NDIM);                   // 32 KB
  unsigned short* P = (unsigned short*)((char*)d_ws + (34ull << 20));  // rest

  const size_t avail = ws_size > (34ull << 20) ? ws_size - (34ull << 20) : 0;
  int nc = 1;
  while (nc < 64 && ((size_t)(NROWS / nc) * NROWS * 2) > avail) nc <<= 1;
  const int RC = NROWS / nc;

  hipMemsetAsync(lsum, 0, NROWS * sizeof(float), stream);
  k_norm<<<NROWS, 256, 0, stream>>>(emb, xb);
  k_tr<<<dim3(NROWS / 64, NDIM / 64), 256, 0, stream>>>(emb, Vt);

  if (nc == 1) {
    const int nt = NROWS / 128;
    k_s_sym<<<nt * (nt + 1) / 2, 256, 0, stream>>>(xb, P, lsum);
    k_pvT<<<dim3(NDIM / 128, NROWS / 128), 256, 0, stream>>>(P, Vt, lsum, out, 0);
  } else {
    for (int c = 0; c < nc; ++c) {
      const int ch0 = c * RC;
      k_s_full<<<dim3(RC / 128, NROWS / 128), 256, 0, stream>>>(xb, P, lsum, ch0);
      k_pvT<<<dim3(NDIM / 128, RC / 128), 256, 0, stream>>>(P, Vt, lsum, out, ch0);
    }
  }
}

// Round 4
// 420.952 us; speedup vs baseline: 3.3381x; 1.3194x over previous
//
#include <hip/hip_runtime.h>
#include <hip/hip_bf16.h>

#define NROWS 8192
#define NDIM  1024
#define ESCALE 8192.0f
#define EINV   (1.0f / 8192.0f)

typedef __attribute__((ext_vector_type(8))) short short8;
typedef __attribute__((ext_vector_type(4))) float floatx4;

__device__ __forceinline__ unsigned short f2b(float f) {
  union { float f; unsigned int u; } v; v.f = f;
  unsigned int r = v.u + 0x7fffu + ((v.u >> 16) & 1u);
  return (unsigned short)(r >> 16);
}

__device__ __forceinline__ void async16(void* lds, const void* g) {
  __builtin_amdgcn_global_load_lds(
      (const __attribute__((address_space(1))) unsigned int*)g,
      (__attribute__((address_space(3))) unsigned int*)lds, 16, 0, 0);
}

// pack one float -> fp8 e4m3 byte
__device__ __forceinline__ unsigned char f2f8(float f) {
  return (unsigned char)(__builtin_amdgcn_cvt_pk_fp8_f32(f, 0.f, 0, false) & 0xff);
}

// ---------------- Kernel 1: row L2-normalize -> bf16 x ----------------
__global__ __launch_bounds__(256) void k_norm(const float* __restrict__ emb,
                                              unsigned short* __restrict__ xb) {
  __shared__ float red[4];
  __shared__ float s_rinv;
  const int row = blockIdx.x;
  const int t = threadIdx.x;
  const float4 v = reinterpret_cast<const float4*>(emb + (size_t)row * NDIM)[t];
  float ss = v.x * v.x + v.y * v.y + v.z * v.z + v.w * v.w;
#pragma unroll
  for (int off = 32; off > 0; off >>= 1) ss += __shfl_down(ss, off);
  if ((t & 63) == 0) red[t >> 6] = ss;
  __syncthreads();
  if (t == 0) s_rinv = 1.0f / fmaxf(sqrtf(red[0] + red[1] + red[2] + red[3]), 1e-12f);
  __syncthreads();
  const float rinv = s_rinv;
  ushort4 xo;
  xo.x = f2b(v.x * rinv); xo.y = f2b(v.y * rinv);
  xo.z = f2b(v.z * rinv); xo.w = f2b(v.w * rinv);
  reinterpret_cast<ushort4*>(xb + (size_t)row * NDIM)[t] = xo;
}

// ---------------- Kernel 2: transpose emb -> Vt fp8 [NDIM][NROWS] ----------
__global__ __launch_bounds__(256) void k_tr8(const float* __restrict__ emb,
                                             unsigned char* __restrict__ Vt8) {
  __shared__ float T[64][72];  // [d][r], pad 8
  const int r0 = blockIdx.x * 64;
  const int c0 = blockIdx.y * 64;
  const int t = threadIdx.x;
#pragma unroll
  for (int p = 0; p < 4; ++p) {
    const int r = (t >> 4) + 16 * p;
    const int c = (t & 15) * 4;
    const float4 v = *reinterpret_cast<const float4*>(emb + (size_t)(r0 + r) * NDIM + c0 + c);
    T[c + 0][r] = v.x; T[c + 1][r] = v.y; T[c + 2][r] = v.z; T[c + 3][r] = v.w;
  }
  __syncthreads();
#pragma unroll
  for (int p = 0; p < 2; ++p) {
    const int d = (t >> 3) + 32 * p;
    const int seg = t & 7;
    const float* src = &T[d][seg * 8];
    int w0 = __builtin_amdgcn_cvt_pk_fp8_f32(src[0], src[1], 0, false);
    w0 = __builtin_amdgcn_cvt_pk_fp8_f32(src[2], src[3], w0, true);
    int w1 = __builtin_amdgcn_cvt_pk_fp8_f32(src[4], src[5], 0, false);
    w1 = __builtin_amdgcn_cvt_pk_fp8_f32(src[6], src[7], w1, true);
    int2 o; o.x = w0; o.y = w1;
    *reinterpret_cast<int2*>(Vt8 + (size_t)(c0 + d) * NROWS + r0 + seg * 8) = o;
  }
}

// ---- Kernel 3a: symmetric S -> E=exp(10S-10)-diag, fp8*2^13, triangle grid --
__global__ __launch_bounds__(256) void k_s_sym(const unsigned short* __restrict__ xb,
                                               unsigned char* __restrict__ E,
                                               float* __restrict__ lsum) {
  __shared__ __align__(16) unsigned short As[4 * 128 * 8];
  __shared__ __align__(16) unsigned short Bs[4 * 128 * 8];
  const int tid = threadIdx.x;
  const int lane = tid & 63, w = tid >> 6;
  const int quad = lane >> 4, l15 = lane & 15;
  const int wi = w >> 1, wj = w & 1;

  const int idx = blockIdx.x;
  int bj = (int)((sqrtf(8.0f * idx + 1.0f) - 1.0f) * 0.5f);
  while ((bj + 1) * (bj + 2) / 2 <= idx) ++bj;
  while (bj * (bj + 1) / 2 > idx) --bj;
  const int bi = idx - bj * (bj + 1) / 2;
  const int it0 = bi * 128, jt0 = bj * 128;

  floatx4 acc[4][4];
#pragma unroll
  for (int a = 0; a < 4; ++a)
#pragma unroll
    for (int b = 0; b < 4; ++b) acc[a][b] = {0.f, 0.f, 0.f, 0.f};

  const unsigned short* gA = xb + (size_t)(it0 + lane) * NDIM + w * 8;
  const unsigned short* gB = xb + (size_t)(jt0 + lane) * NDIM + w * 8;
  unsigned short* lA = As + w * 1024;
  unsigned short* lB = Bs + w * 1024;

  for (int k0 = 0; k0 < NDIM; k0 += 32) {
    async16(lA, gA);
    async16(lA + 512, gA + 64 * NDIM);
    async16(lB, gB);
    async16(lB + 512, gB + 64 * NDIM);
    gA += 32; gB += 32;
    __syncthreads();
    short8 af[4], bfr[4];
#pragma unroll
    for (int fm = 0; fm < 4; ++fm)
      af[fm] = *reinterpret_cast<const short8*>(As + quad * 1024 + (wi * 64 + fm * 16 + l15) * 8);
#pragma unroll
    for (int fn = 0; fn < 4; ++fn)
      bfr[fn] = *reinterpret_cast<const short8*>(Bs + quad * 1024 + (wj * 64 + fn * 16 + l15) * 8);
#pragma unroll
    for (int fm = 0; fm < 4; ++fm)
#pragma unroll
      for (int fn = 0; fn < 4; ++fn)
        acc[fm][fn] = __builtin_amdgcn_mfma_f32_16x16x32_bf16(af[fm], bfr[fn], acc[fm][fn], 0, 0, 0);
    __syncthreads();
  }

  // E = exp(10 s - 10); diag element of diag tiles -> 0
#pragma unroll
  for (int fm = 0; fm < 4; ++fm)
#pragma unroll
    for (int fn = 0; fn < 4; ++fn)
#pragma unroll
      for (int reg = 0; reg < 4; ++reg) {
        float p = __expf(fmaf(acc[fm][fn][reg], 10.f, -10.f));
        if (bi == bj &&
            (wi * 64 + fm * 16 + quad * 4 + reg) == (wj * 64 + fn * 16 + l15))
          p = 0.f;
        acc[fm][fn][reg] = p;
      }

  // normal-orientation byte stores + row sums (off-diag only)
#pragma unroll
  for (int fm = 0; fm < 4; ++fm)
#pragma unroll
    for (int reg = 0; reg < 4; ++reg) {
      const int row = wi * 64 + fm * 16 + quad * 4 + reg;
      float s = 0.f;
#pragma unroll
      for (int fn = 0; fn < 4; ++fn) {
        const float p = acc[fm][fn][reg];
        s += p;
        E[(size_t)(it0 + row) * NROWS + jt0 + wj * 64 + fn * 16 + l15] = f2f8(p * ESCALE);
      }
#pragma unroll
      for (int m = 1; m < 16; m <<= 1) s += __shfl_xor(s, m);
      if (l15 == 0) unsafeAtomicAdd(&lsum[it0 + row], s);
    }

  if (bi != bj) {  // transposed store (uchar4 along i) + col sums
#pragma unroll
    for (int fn = 0; fn < 4; ++fn) {
      const int col = wj * 64 + fn * 16 + l15;
      float cs = 0.f;
#pragma unroll
      for (int fm = 0; fm < 4; ++fm) {
        int pk = __builtin_amdgcn_cvt_pk_fp8_f32(acc[fm][fn][0] * ESCALE,
                                                 acc[fm][fn][1] * ESCALE, 0, false);
        pk = __builtin_amdgcn_cvt_pk_fp8_f32(acc[fm][fn][2] * ESCALE,
                                             acc[fm][fn][3] * ESCALE, pk, true);
        cs += acc[fm][fn][0] + acc[fm][fn][1] + acc[fm][fn][2] + acc[fm][fn][3];
        *reinterpret_cast<int*>(
            &E[(size_t)(jt0 + col) * NROWS + it0 + wi * 64 + fm * 16 + quad * 4]) = pk;
      }
      cs += __shfl_xor(cs, 16);
      cs += __shfl_xor(cs, 32);
      if (quad == 0) unsafeAtomicAdd(&lsum[jt0 + col], cs);
    }
  }
}

// ---------------- Kernel 3b: full-grid fallback (chunked) ----------------
__global__ __launch_bounds__(256) void k_s_full(const unsigned short* __restrict__ xb,
                                                unsigned char* __restrict__ E,
                                                float* __restrict__ lsum, int ch0) {
  __shared__ __align__(16) unsigned short As[4 * 128 * 8];
  __shared__ __align__(16) unsigned short Bs[4 * 128 * 8];
  const int tid = threadIdx.x;
  const int lane = tid & 63, w = tid >> 6;
  const int quad = lane >> 4, l15 = lane & 15;
  const int wi = w >> 1, wj = w & 1;
  const int it0 = blockIdx.x * 128;
  const int jt0 = blockIdx.y * 128;

  floatx4 acc[4][4];
#pragma unroll
  for (int a = 0; a < 4; ++a)
#pragma unroll
    for (int b = 0; b < 4; ++b) acc[a][b] = {0.f, 0.f, 0.f, 0.f};

  const unsigned short* gA = xb + (size_t)(ch0 + it0 + lane) * NDIM + w * 8;
  const unsigned short* gB = xb + (size_t)(jt0 + lane) * NDIM + w * 8;
  unsigned short* lA = As + w * 1024;
  unsigned short* lB = Bs + w * 1024;

  for (int k0 = 0; k0 < NDIM; k0 += 32) {
    async16(lA, gA);
    async16(lA + 512, gA + 64 * NDIM);
    async16(lB, gB);
    async16(lB + 512, gB + 64 * NDIM);
    gA += 32; gB += 32;
    __syncthreads();
    short8 af[4], bfr[4];
#pragma unroll
    for (int fm = 0; fm < 4; ++fm)
      af[fm] = *reinterpret_cast<const short8*>(As + quad * 1024 + (wi * 64 + fm * 16 + l15) * 8);
#pragma unroll
    for (int fn = 0; fn < 4; ++fn)
      bfr[fn] = *reinterpret_cast<const short8*>(Bs + quad * 1024 + (wj * 64 + fn * 16 + l15) * 8);
#pragma unroll
    for (int fm = 0; fm < 4; ++fm)
#pragma unroll
      for (int fn = 0; fn < 4; ++fn)
        acc[fm][fn] = __builtin_amdgcn_mfma_f32_16x16x32_bf16(af[fm], bfr[fn], acc[fm][fn], 0, 0, 0);
    __syncthreads();
  }

#pragma unroll
  for (int fm = 0; fm < 4; ++fm)
#pragma unroll
    for (int reg = 0; reg < 4; ++reg) {
      const int row = wi * 64 + fm * 16 + quad * 4 + reg;
      float s = 0.f;
#pragma unroll
      for (int fn = 0; fn < 4; ++fn) {
        const int col = jt0 + wj * 64 + fn * 16 + l15;
        float p = __expf(fmaf(acc[fm][fn][reg], 10.f, -10.f));
        if (ch0 + it0 + row == col) p = 0.f;
        s += p;
        E[(size_t)(it0 + row) * NROWS + col] = f2f8(p * ESCALE);
      }
#pragma unroll
      for (int m = 1; m < 16; m <<= 1) s += __shfl_xor(s, m);
      if (l15 == 0) unsafeAtomicAdd(&lsum[ch0 + it0 + row], s);
    }
}

// -------- Kernel 4: out^T = Vt8 @ E^T (fp8 MFMA), + identity, /(1+esum) -----
// swz=1: 1-D grid of 512, remapped so the 8 d-tiles of an i-tile share an XCD.
__global__ __launch_bounds__(256, 2) void k_pv8(const unsigned char* __restrict__ E,
                                                const unsigned char* __restrict__ Vt8,
                                                const float* __restrict__ lsum,
                                                const float* __restrict__ emb,
                                                float* __restrict__ out,
                                                int swz, int ch0) {
  __shared__ __align__(16) unsigned char As[4 * 128 * 16];  // [ks16][row][16B], 8 KB
  __shared__ __align__(16) unsigned char Bs[4 * 128 * 16];
  const int tid = threadIdx.x;
  const int lane = tid & 63, w = tid >> 6;
  const int quad = lane >> 4, l15 = lane & 15;
  const int wi = w >> 1, wj = w & 1;

  int dt, it;
  if (swz) {
    const int n = blockIdx.x;
    const int r = n & 7, q = n >> 3;
    dt = q >> 3; it = (q & 7) * 8 + r;
  } else {
    dt = blockIdx.x; it = blockIdx.y;
  }
  const int dt0 = dt * 128, it0 = it * 128;

  floatx4 acc[4][4];
#pragma unroll
  for (int a = 0; a < 4; ++a)
#pragma unroll
    for (int b = 0; b < 4; ++b) acc[a][b] = {0.f, 0.f, 0.f, 0.f};

  // staging: wave w fills kseg16 w (k bytes [w*16, w*16+16)) of both tiles,
  // two calls per side covering rows [0,64) and [64,128).
  const unsigned char* gA0 = Vt8 + (size_t)(dt0 + lane) * NROWS + w * 16;
  const unsigned char* gA1 = Vt8 + (size_t)(dt0 + 64 + lane) * NROWS + w * 16;
  const unsigned char* gB0 = E + (size_t)(it0 + lane) * NROWS + w * 16;
  const unsigned char* gB1 = E + (size_t)(it0 + 64 + lane) * NROWS + w * 16;
  unsigned char* lA = As + w * 2048;
  unsigned char* lB = Bs + w * 2048;

  for (int k0 = 0; k0 < NROWS; k0 += 64) {
    async16(lA, gA0);
    async16(lA + 1024, gA1);
    async16(lB, gB0);
    async16(lB + 1024, gB1);
    gA0 += 64; gA1 += 64; gB0 += 64; gB1 += 64;
    __syncthreads();
#pragma unroll
    for (int s = 0; s < 2; ++s) {
      const int ks16 = s * 2 + (quad >> 1);
      const int inner = (quad & 1) * 8;
      long long af[4], bfr[4];
#pragma unroll
      for (int fm = 0; fm < 4; ++fm)
        af[fm] = *reinterpret_cast<const long long*>(
            As + ks16 * 2048 + (wi * 64 + fm * 16 + l15) * 16 + inner);
#pragma unroll
      for (int fn = 0; fn < 4; ++fn)
        bfr[fn] = *reinterpret_cast<const long long*>(
            Bs + ks16 * 2048 + (wj * 64 + fn * 16 + l15) * 16 + inner);
#pragma unroll
      for (int fm = 0; fm < 4; ++fm)
#pragma unroll
        for (int fn = 0; fn < 4; ++fn)
          acc[fm][fn] = __builtin_amdgcn_mfma_f32_16x16x32_fp8_fp8(af[fm], bfr[fn], acc[fm][fn], 0, 0, 0);
    }
    __syncthreads();
  }

#pragma unroll
  for (int fn = 0; fn < 4; ++fn) {
    const int i = it0 + wj * 64 + fn * 16 + l15;
    const float rinv = 1.0f / (1.0f + lsum[ch0 + i]);
#pragma unroll
    for (int fm = 0; fm < 4; ++fm) {
      const int d = dt0 + wi * 64 + fm * 16 + quad * 4;
      const float4 e = *reinterpret_cast<const float4*>(emb + (size_t)(ch0 + i) * NDIM + d);
      float4 o;
      o.x = (e.x + acc[fm][fn][0] * EINV) * rinv;
      o.y = (e.y + acc[fm][fn][1] * EINV) * rinv;
      o.z = (e.z + acc[fm][fn][2] * EINV) * rinv;
      o.w = (e.w + acc[fm][fn][3] * EINV) * rinv;
      *reinterpret_cast<float4*>(out + (size_t)(ch0 + i) * NDIM + d) = o;
    }
  }
}

extern "C" void kernel_launch(void* const* d_in, const int* in_sizes, int n_in,
                              void* d_out, int out_size, void* d_ws, size_t ws_size,
                              hipStream_t stream) {
  const float* emb = (const float*)d_in[0];
  float* out = (float*)d_out;

  unsigned short* xb = (unsigned short*)d_ws;                           // 16 MB
  unsigned char* Vt8 = (unsigned char*)((char*)d_ws + (16ull << 20));   // 8 MB
  float* lsum = (float*)((char*)d_ws + (24ull << 20));                  // 32 KB
  unsigned char* E = (unsigned char*)((char*)d_ws + (25ull << 20));     // 64 MB

  const size_t avail = ws_size > (25ull << 20) ? ws_size - (25ull << 20) : 0;
  int nc = 1;
  while (nc < 64 && ((size_t)(NROWS / nc) * NROWS) > avail) nc <<= 1;
  const int RC = NROWS / nc;

  hipMemsetAsync(lsum, 0, NROWS * sizeof(float), stream);
  k_norm<<<NROWS, 256, 0, stream>>>(emb, xb);
  k_tr8<<<dim3(NROWS / 64, NDIM / 64), 256, 0, stream>>>(emb, Vt8);

  if (nc == 1) {
    const int nt = NROWS / 128;
    k_s_sym<<<nt * (nt + 1) / 2, 256, 0, stream>>>(xb, E, lsum);
    k_pv8<<<512, 256, 0, stream>>>(E, Vt8, lsum, emb, out, 1, 0);
  } else {
    for (int c = 0; c < nc; ++c) {
      const int ch0 = c * RC;
      k_s_full<<<dim3(RC / 128, NROWS / 128), 256, 0, stream>>>(xb, E, lsum, ch0);
      k_pv8<<<dim3(NDIM / 128, RC / 128), 256, 0, stream>>>(E, Vt8, lsum, emb, out, 0, ch0);
    }
  }
}

// Round 7
// 337.105 us; speedup vs baseline: 4.1684x; 1.2487x over previous
//
#include <hip/hip_runtime.h>
#include <hip/hip_bf16.h>

#define NROWS 8192
#define NDIM  1024
#define ESCALE 8192.0f
#define EINV   (1.0f / 8192.0f)

// packed tile constants
#define XTILE_SH 131072ull   // shorts per packed xb tile: 128 rows * 1024 k
#define PTILE_B  1048576ull  // bytes per packed fp8 tile: 128 rows * 8192 k

typedef __attribute__((ext_vector_type(8))) short short8;
typedef __attribute__((ext_vector_type(4))) float floatx4;

__device__ __forceinline__ unsigned short f2b(float f) {
  union { float f; unsigned int u; } v; v.f = f;
  unsigned int r = v.u + 0x7fffu + ((v.u >> 16) & 1u);
  return (unsigned short)(r >> 16);
}

// async global->LDS. PER-LANE gather: lane l loads 16B from its own g (pass
// base + lane*16!) and HW writes to lds_base + lane*16 (lds base wave-uniform).
__device__ __forceinline__ void async16(void* lds, const void* g) {
  __builtin_amdgcn_global_load_lds(
      (const __attribute__((address_space(1))) unsigned int*)g,
      (__attribute__((address_space(3))) unsigned int*)lds, 16, 0, 0);
}

__device__ __forceinline__ unsigned char f2f8(float f) {
  return (unsigned char)(__builtin_amdgcn_cvt_pk_fp8_f32(f, 0.f, 0, false) & 0xff);
}

// ------- Kernel 1: row L2-normalize -> bf16 x, TILE-PACKED layout ----------
// packed short index within tile: (k>>3)*1024 + (row&127)*8 + (k&7)
__global__ __launch_bounds__(256) void k_norm(const float* __restrict__ emb,
                                              unsigned short* __restrict__ xb) {
  __shared__ float red[4];
  __shared__ float s_rinv;
  const int row = blockIdx.x;
  const int t = threadIdx.x;
  const float4 v = reinterpret_cast<const float4*>(emb + (size_t)row * NDIM)[t];
  float ss = v.x * v.x + v.y * v.y + v.z * v.z + v.w * v.w;
#pragma unroll
  for (int off = 32; off > 0; off >>= 1) ss += __shfl_down(ss, off);
  if ((t & 63) == 0) red[t >> 6] = ss;
  __syncthreads();
  if (t == 0) s_rinv = 1.0f / fmaxf(sqrtf(red[0] + red[1] + red[2] + red[3]), 1e-12f);
  __syncthreads();
  const float rinv = s_rinv;
  ushort4 xo;
  xo.x = f2b(v.x * rinv); xo.y = f2b(v.y * rinv);
  xo.z = f2b(v.z * rinv); xo.w = f2b(v.w * rinv);
  const int k = t * 4;
  unsigned short* dst = xb + (size_t)(row >> 7) * XTILE_SH +
                        (k >> 3) * 1024 + (row & 127) * 8 + (k & 7);
  *reinterpret_cast<ushort4*>(dst) = xo;
}

// ------- Kernel 2: transpose emb -> Vt fp8, TILE-PACKED ----------
// packed byte index within tile: (j>>4)*2048 + (d&127)*16 + (j&15)
__global__ __launch_bounds__(256) void k_tr8(const float* __restrict__ emb,
                                             unsigned char* __restrict__ Vt8) {
  __shared__ float T[64][72];
  const int r0 = blockIdx.x * 64;  // source rows (j of Vt)
  const int c0 = blockIdx.y * 64;  // source cols (d of Vt)
  const int t = threadIdx.x;
#pragma unroll
  for (int p = 0; p < 4; ++p) {
    const int r = (t >> 4) + 16 * p;
    const int c = (t & 15) * 4;
    const float4 v = *reinterpret_cast<const float4*>(emb + (size_t)(r0 + r) * NDIM + c0 + c);
    T[c + 0][r] = v.x; T[c + 1][r] = v.y; T[c + 2][r] = v.z; T[c + 3][r] = v.w;
  }
  __syncthreads();
#pragma unroll
  for (int p = 0; p < 2; ++p) {
    const int d = (t >> 3) + 32 * p;
    const int seg = t & 7;
    const float* src = &T[d][seg * 8];
    int w0 = __builtin_amdgcn_cvt_pk_fp8_f32(src[0], src[1], 0, false);
    w0 = __builtin_amdgcn_cvt_pk_fp8_f32(src[2], src[3], w0, true);
    int w1 = __builtin_amdgcn_cvt_pk_fp8_f32(src[4], src[5], 0, false);
    w1 = __builtin_amdgcn_cvt_pk_fp8_f32(src[6], src[7], w1, true);
    const int dg = c0 + d;          // global d
    const int jg = r0 + seg * 8;    // global j
    unsigned char* dst = Vt8 + (size_t)(dg >> 7) * PTILE_B +
                         (jg >> 4) * 2048 + (dg & 127) * 16 + (jg & 15);
    int2 o; o.x = w0; o.y = w1;
    *reinterpret_cast<int2*>(dst) = o;
  }
}

// ---- Kernel 3a: symmetric S -> E fp8 (packed), triangle grid ----
__global__ __launch_bounds__(256) void k_s_sym(const unsigned short* __restrict__ xb,
                                               unsigned char* __restrict__ E,
                                               float* __restrict__ lsum) {
  __shared__ __align__(16) unsigned short As[4 * 128 * 8];
  __shared__ __align__(16) unsigned short Bs[4 * 128 * 8];
  const int tid = threadIdx.x;
  const int lane = tid & 63, w = tid >> 6;
  const int quad = lane >> 4, l15 = lane & 15;
  const int wi = w >> 1, wj = w & 1;

  const int idx = blockIdx.x;
  int bj = (int)((sqrtf(8.0f * idx + 1.0f) - 1.0f) * 0.5f);
  while ((bj + 1) * (bj + 2) / 2 <= idx) ++bj;
  while (bj * (bj + 1) / 2 > idx) --bj;
  const int bi = idx - bj * (bj + 1) / 2;
  const int it0 = bi * 128, jt0 = bj * 128;

  floatx4 acc[4][4];
#pragma unroll
  for (int a = 0; a < 4; ++a)
#pragma unroll
    for (int b = 0; b < 4; ++b) acc[a][b] = {0.f, 0.f, 0.f, 0.f};

  // packed staging, PER-LANE addresses: wave w stages kseg w, lane l row l
  const unsigned short* gA = xb + (size_t)bi * XTILE_SH + w * 1024 + lane * 8;
  const unsigned short* gB = xb + (size_t)bj * XTILE_SH + w * 1024 + lane * 8;
  unsigned short* lA = As + w * 1024;
  unsigned short* lB = Bs + w * 1024;

  for (int k0 = 0; k0 < NDIM; k0 += 32) {
    async16(lA, gA);
    async16(lA + 512, gA + 512);
    async16(lB, gB);
    async16(lB + 512, gB + 512);
    gA += 4096; gB += 4096;
    __syncthreads();
    short8 af[4], bfr[4];
#pragma unroll
    for (int fm = 0; fm < 4; ++fm)
      af[fm] = *reinterpret_cast<const short8*>(As + quad * 1024 + (wi * 64 + fm * 16 + l15) * 8);
#pragma unroll
    for (int fn = 0; fn < 4; ++fn)
      bfr[fn] = *reinterpret_cast<const short8*>(Bs + quad * 1024 + (wj * 64 + fn * 16 + l15) * 8);
#pragma unroll
    for (int fm = 0; fm < 4; ++fm)
#pragma unroll
      for (int fn = 0; fn < 4; ++fn)
        acc[fm][fn] = __builtin_amdgcn_mfma_f32_16x16x32_bf16(af[fm], bfr[fn], acc[fm][fn], 0, 0, 0);
    __syncthreads();
  }

  // E = exp(10 s - 10); zero the true diagonal
#pragma unroll
  for (int fm = 0; fm < 4; ++fm)
#pragma unroll
    for (int fn = 0; fn < 4; ++fn)
#pragma unroll
      for (int reg = 0; reg < 4; ++reg) {
        float p = __expf(fmaf(acc[fm][fn][reg], 10.f, -10.f));
        if (bi == bj &&
            (wi * 64 + fm * 16 + quad * 4 + reg) == (wj * 64 + fn * 16 + l15))
          p = 0.f;
        acc[fm][fn][reg] = p;
      }

  // normal-orientation packed stores + row sums
  unsigned char* Ei = E + (size_t)bi * PTILE_B;
#pragma unroll
  for (int fm = 0; fm < 4; ++fm)
#pragma unroll
    for (int reg = 0; reg < 4; ++reg) {
      const int row = wi * 64 + fm * 16 + quad * 4 + reg;
      float s = 0.f;
#pragma unroll
      for (int fn = 0; fn < 4; ++fn) {
        const float p = acc[fm][fn][reg];
        s += p;
        Ei[((jt0 >> 4) + wj * 4 + fn) * 2048 + row * 16 + l15] = f2f8(p * ESCALE);
      }
#pragma unroll
      for (int m = 1; m < 16; m <<= 1) s += __shfl_xor(s, m);
      if (l15 == 0) unsafeAtomicAdd(&lsum[it0 + row], s);
    }

  if (bi != bj) {  // transposed packed store + col sums
    unsigned char* Ej = E + (size_t)bj * PTILE_B;
#pragma unroll
    for (int fn = 0; fn < 4; ++fn) {
      const int col = wj * 64 + fn * 16 + l15;  // i-local row within tile bj
      float cs = 0.f;
#pragma unroll
      for (int fm = 0; fm < 4; ++fm) {
        int pk = __builtin_amdgcn_cvt_pk_fp8_f32(acc[fm][fn][0] * ESCALE,
                                                 acc[fm][fn][1] * ESCALE, 0, false);
        pk = __builtin_amdgcn_cvt_pk_fp8_f32(acc[fm][fn][2] * ESCALE,
                                             acc[fm][fn][3] * ESCALE, pk, true);
        cs += acc[fm][fn][0] + acc[fm][fn][1] + acc[fm][fn][2] + acc[fm][fn][3];
        // k-dim (original i) = it0 + wi*64 + fm*16 + quad*4 + (0..3)
        *reinterpret_cast<int*>(
            &Ej[((it0 >> 4) + wi * 4 + fm) * 2048 + col * 16 + quad * 4]) = pk;
      }
      cs += __shfl_xor(cs, 16);
      cs += __shfl_xor(cs, 32);
      if (quad == 0) unsafeAtomicAdd(&lsum[jt0 + col], cs);
    }
  }
}

// ---------------- Kernel 3b: full-grid fallback (chunked, packed) ----------
__global__ __launch_bounds__(256) void k_s_full(const unsigned short* __restrict__ xb,
                                                unsigned char* __restrict__ E,
                                                float* __restrict__ lsum, int ch0) {
  __shared__ __align__(16) unsigned short As[4 * 128 * 8];
  __shared__ __align__(16) unsigned short Bs[4 * 128 * 8];
  const int tid = threadIdx.x;
  const int lane = tid & 63, w = tid >> 6;
  const int quad = lane >> 4, l15 = lane & 15;
  const int wi = w >> 1, wj = w & 1;
  const int bi = blockIdx.x;       // chunk-local i tile
  const int bj = blockIdx.y;       // global j tile
  const int it0 = bi * 128, jt0 = bj * 128;

  floatx4 acc[4][4];
#pragma unroll
  for (int a = 0; a < 4; ++a)
#pragma unroll
    for (int b = 0; b < 4; ++b) acc[a][b] = {0.f, 0.f, 0.f, 0.f};

  const unsigned short* gA =
      xb + (size_t)((ch0 >> 7) + bi) * XTILE_SH + w * 1024 + lane * 8;
  const unsigned short* gB = xb + (size_t)bj * XTILE_SH + w * 1024 + lane * 8;
  unsigned short* lA = As + w * 1024;
  unsigned short* lB = Bs + w * 1024;

  for (int k0 = 0; k0 < NDIM; k0 += 32) {
    async16(lA, gA);
    async16(lA + 512, gA + 512);
    async16(lB, gB);
    async16(lB + 512, gB + 512);
    gA += 4096; gB += 4096;
    __syncthreads();
    short8 af[4], bfr[4];
#pragma unroll
    for (int fm = 0; fm < 4; ++fm)
      af[fm] = *reinterpret_cast<const short8*>(As + quad * 1024 + (wi * 64 + fm * 16 + l15) * 8);
#pragma unroll
    for (int fn = 0; fn < 4; ++fn)
      bfr[fn] = *reinterpret_cast<const short8*>(Bs + quad * 1024 + (wj * 64 + fn * 16 + l15) * 8);
#pragma unroll
    for (int fm = 0; fm < 4; ++fm)
#pragma unroll
      for (int fn = 0; fn < 4; ++fn)
        acc[fm][fn] = __builtin_amdgcn_mfma_f32_16x16x32_bf16(af[fm], bfr[fn], acc[fm][fn], 0, 0, 0);
    __syncthreads();
  }

  unsigned char* Ei = E + (size_t)bi * PTILE_B;
#pragma unroll
  for (int fm = 0; fm < 4; ++fm)
#pragma unroll
    for (int reg = 0; reg < 4; ++reg) {
      const int row = wi * 64 + fm * 16 + quad * 4 + reg;
      float s = 0.f;
#pragma unroll
      for (int fn = 0; fn < 4; ++fn) {
        const int col = jt0 + wj * 64 + fn * 16 + l15;
        float p = __expf(fmaf(acc[fm][fn][reg], 10.f, -10.f));
        if (ch0 + it0 + row == col) p = 0.f;
        s += p;
        Ei[(col >> 4) * 2048 + row * 16 + (col & 15)] = f2f8(p * ESCALE);
      }
#pragma unroll
      for (int m = 1; m < 16; m <<= 1) s += __shfl_xor(s, m);
      if (l15 == 0) unsafeAtomicAdd(&lsum[ch0 + it0 + row], s);
    }
}

// -------- Kernel 4: out^T = Vt8 @ E^T (fp8 MFMA, both operands packed) ------
__global__ __launch_bounds__(256, 2) void k_pv8(const unsigned char* __restrict__ E,
                                                const unsigned char* __restrict__ Vt8,
                                                const float* __restrict__ lsum,
                                                const float* __restrict__ emb,
                                                float* __restrict__ out,
                                                int swz, int ch0) {
  __shared__ __align__(16) unsigned char As[4 * 128 * 16];  // [jseg16][row][16B]
  __shared__ __align__(16) unsigned char Bs[4 * 128 * 16];
  const int tid = threadIdx.x;
  const int lane = tid & 63, w = tid >> 6;
  const int quad = lane >> 4, l15 = lane & 15;
  const int wi = w >> 1, wj = w & 1;

  int dt, it;
  if (swz) {
    const int n = blockIdx.x;
    const int r = n & 7, q = n >> 3;
    dt = q >> 3; it = (q & 7) * 8 + r;
  } else {
    dt = blockIdx.x; it = blockIdx.y;
  }
  const int dt0 = dt * 128, it0 = it * 128;

  floatx4 acc[4][4];
#pragma unroll
  for (int a = 0; a < 4; ++a)
#pragma unroll
    for (int b = 0; b < 4; ++b) acc[a][b] = {0.f, 0.f, 0.f, 0.f};

  // packed staging, PER-LANE addresses: wave w stages jseg16 w, lane l row l
  const unsigned char* gA = Vt8 + (size_t)dt * PTILE_B + w * 2048 + lane * 16;
  const unsigned char* gB = E + (size_t)it * PTILE_B + w * 2048 + lane * 16;
  unsigned char* lA = As + w * 2048;
  unsigned char* lB = Bs + w * 2048;

  for (int k0 = 0; k0 < NROWS; k0 += 64) {
    async16(lA, gA);
    async16(lA + 1024, gA + 1024);
    async16(lB, gB);
    async16(lB + 1024, gB + 1024);
    gA += 8192; gB += 8192;
    __syncthreads();
#pragma unroll
    for (int s = 0; s < 2; ++s) {
      const int ks16 = s * 2 + (quad >> 1);
      const int inner = (quad & 1) * 8;
      long long af[4], bfr[4];
#pragma unroll
      for (int fm = 0; fm < 4; ++fm)
        af[fm] = *reinterpret_cast<const long long*>(
            As + ks16 * 2048 + (wi * 64 + fm * 16 + l15) * 16 + inner);
#pragma unroll
      for (int fn = 0; fn < 4; ++fn)
        bfr[fn] = *reinterpret_cast<const long long*>(
            Bs + ks16 * 2048 + (wj * 64 + fn * 16 + l15) * 16 + inner);
#pragma unroll
      for (int fm = 0; fm < 4; ++fm)
#pragma unroll
        for (int fn = 0; fn < 4; ++fn)
          acc[fm][fn] = __builtin_amdgcn_mfma_f32_16x16x32_fp8_fp8(af[fm], bfr[fn], acc[fm][fn], 0, 0, 0);
    }
    __syncthreads();
  }

#pragma unroll
  for (int fn = 0; fn < 4; ++fn) {
    const int i = it0 + wj * 64 + fn * 16 + l15;
    const float rinv = 1.0f / (1.0f + lsum[ch0 + i]);
#pragma unroll
    for (int fm = 0; fm < 4; ++fm) {
      const int d = dt0 + wi * 64 + fm * 16 + quad * 4;
      const float4 e = *reinterpret_cast<const float4*>(emb + (size_t)(ch0 + i) * NDIM + d);
      float4 o;
      o.x = (e.x + acc[fm][fn][0] * EINV) * rinv;
      o.y = (e.y + acc[fm][fn][1] * EINV) * rinv;
      o.z = (e.z + acc[fm][fn][2] * EINV) * rinv;
      o.w = (e.w + acc[fm][fn][3] * EINV) * rinv;
      *reinterpret_cast<float4*>(out + (size_t)(ch0 + i) * NDIM + d) = o;
    }
  }
}

extern "C" void kernel_launch(void* const* d_in, const int* in_sizes, int n_in,
                              void* d_out, int out_size, void* d_ws, size_t ws_size,
                              hipStream_t stream) {
  const float* emb = (const float*)d_in[0];
  float* out = (float*)d_out;

  unsigned short* xb = (unsigned short*)d_ws;                           // 16 MB packed
  unsigned char* Vt8 = (unsigned char*)((char*)d_ws + (16ull << 20));   // 8 MB packed
  float* lsum = (float*)((char*)d_ws + (24ull << 20));                  // 32 KB
  unsigned char* E = (unsigned char*)((char*)d_ws + (25ull << 20));     // 64 MB packed

  const size_t avail = ws_size > (25ull << 20) ? ws_size - (25ull << 20) : 0;
  int nc = 1;
  while (nc < 64 && ((size_t)(NROWS / nc) * NROWS) > avail) nc <<= 1;
  const int RC = NROWS / nc;

  hipMemsetAsync(lsum, 0, NROWS * sizeof(float), stream);
  k_norm<<<NROWS, 256, 0, stream>>>(emb, xb);
  k_tr8<<<dim3(NROWS / 64, NDIM / 64), 256, 0, stream>>>(emb, Vt8);

  if (nc == 1) {
    const int nt = NROWS / 128;
    k_s_sym<<<nt * (nt + 1) / 2, 256, 0, stream>>>(xb, E, lsum);
    k_pv8<<<512, 256, 0, stream>>>(E, Vt8, lsum, emb, out, 1, 0);
  } else {
    for (int c = 0; c < nc; ++c) {
      const int ch0 = c * RC;
      k_s_full<<<dim3(RC / 128, NROWS / 128), 256, 0, stream>>>(xb, E, lsum, ch0);
      k_pv8<<<dim3(NDIM / 128, RC / 128), 256, 0, stream>>>(E, Vt8, lsum, emb, out, 0, ch0);
    }
  }
}

// Round 8
// 273.808 us; speedup vs baseline: 5.1320x; 1.2312x over previous
//
#include <hip/hip_runtime.h>
#include <hip/hip_bf16.h>

#define NROWS 8192
#define NDIM  1024
#define ESCALE 8192.0f
#define EINV   (1.0f / 8192.0f)
#define SCALE1 0x7F7F7F7F   // e8m0 = 127 -> 2^0 in every byte

// packed tile constants (16B-inner layout: [kseg16][row(128)][16B])
#define XTILE_B  131072ull   // bytes per packed fp8 x tile: 128 rows * 1024 k
#define PTILE_B  1048576ull  // bytes per packed fp8 E/Vt tile: 128 rows * 8192 k

typedef __attribute__((ext_vector_type(8))) int intx8;
typedef __attribute__((ext_vector_type(4))) int intx4;
typedef __attribute__((ext_vector_type(4))) float floatx4;

// async global->LDS. PER-LANE gather: lane l loads 16B from g + l*16 only if
// you pass per-lane addresses; HW writes to lds_base + lane*16.
__device__ __forceinline__ void async16(void* lds, const void* g) {
  __builtin_amdgcn_global_load_lds(
      (const __attribute__((address_space(1))) unsigned int*)g,
      (__attribute__((address_space(3))) unsigned int*)lds, 16, 0, 0);
}

__device__ __forceinline__ unsigned char f2f8(float f) {
  return (unsigned char)(__builtin_amdgcn_cvt_pk_fp8_f32(f, 0.f, 0, false) & 0xff);
}

// read a 32-byte A/B fragment (k = quad*32..+31) from a 16B-inner LDS tile
__device__ __forceinline__ intx8 frag32(const unsigned char* base, int quad, int row) {
  const intx4 lo = *reinterpret_cast<const intx4*>(base + (2 * quad) * 2048 + row * 16);
  const intx4 hi = *reinterpret_cast<const intx4*>(base + (2 * quad + 1) * 2048 + row * 16);
  return __builtin_shufflevector(lo, hi, 0, 1, 2, 3, 4, 5, 6, 7);
}

// ------- Kernel 1: row L2-normalize -> fp8(16*x), TILE-PACKED ----------
// byte index within tile: (k>>4)*2048 + (row&127)*16 + (k&15)
__global__ __launch_bounds__(256) void k_norm(const float* __restrict__ emb,
                                              unsigned char* __restrict__ xb) {
  __shared__ float red[4];
  __shared__ float s_rinv;
  const int row = blockIdx.x;
  const int t = threadIdx.x;
  const float4 v = reinterpret_cast<const float4*>(emb + (size_t)row * NDIM)[t];
  float ss = v.x * v.x + v.y * v.y + v.z * v.z + v.w * v.w;
#pragma unroll
  for (int off = 32; off > 0; off >>= 1) ss += __shfl_down(ss, off);
  if ((t & 63) == 0) red[t >> 6] = ss;
  __syncthreads();
  if (t == 0) s_rinv = 1.0f / fmaxf(sqrtf(red[0] + red[1] + red[2] + red[3]), 1e-12f);
  __syncthreads();
  const float r16 = 16.0f * s_rinv;
  int pk = __builtin_amdgcn_cvt_pk_fp8_f32(v.x * r16, v.y * r16, 0, false);
  pk = __builtin_amdgcn_cvt_pk_fp8_f32(v.z * r16, v.w * r16, pk, true);
  const int k = t * 4;
  unsigned char* dst = xb + (size_t)(row >> 7) * XTILE_B +
                       (k >> 4) * 2048 + (row & 127) * 16 + (k & 15);
  *reinterpret_cast<int*>(dst) = pk;
}

// ------- Kernel 2: transpose emb -> Vt fp8, TILE-PACKED ----------
// byte index within tile: (j>>4)*2048 + (d&127)*16 + (j&15)
__global__ __launch_bounds__(256) void k_tr8(const float* __restrict__ emb,
                                             unsigned char* __restrict__ Vt8) {
  __shared__ float T[64][72];
  const int r0 = blockIdx.x * 64;  // source rows (j of Vt)
  const int c0 = blockIdx.y * 64;  // source cols (d of Vt)
  const int t = threadIdx.x;
#pragma unroll
  for (int p = 0; p < 4; ++p) {
    const int r = (t >> 4) + 16 * p;
    const int c = (t & 15) * 4;
    const float4 v = *reinterpret_cast<const float4*>(emb + (size_t)(r0 + r) * NDIM + c0 + c);
    T[c + 0][r] = v.x; T[c + 1][r] = v.y; T[c + 2][r] = v.z; T[c + 3][r] = v.w;
  }
  __syncthreads();
#pragma unroll
  for (int p = 0; p < 2; ++p) {
    const int d = (t >> 3) + 32 * p;
    const int seg = t & 7;
    const float* src = &T[d][seg * 8];
    int w0 = __builtin_amdgcn_cvt_pk_fp8_f32(src[0], src[1], 0, false);
    w0 = __builtin_amdgcn_cvt_pk_fp8_f32(src[2], src[3], w0, true);
    int w1 = __builtin_amdgcn_cvt_pk_fp8_f32(src[4], src[5], 0, false);
    w1 = __builtin_amdgcn_cvt_pk_fp8_f32(src[6], src[7], w1, true);
    const int dg = c0 + d;          // global d
    const int jg = r0 + seg * 8;    // global j
    unsigned char* dst = Vt8 + (size_t)(dg >> 7) * PTILE_B +
                         (jg >> 4) * 2048 + (dg & 127) * 16 + (jg & 15);
    int2 o; o.x = w0; o.y = w1;
    *reinterpret_cast<int2*>(dst) = o;
  }
}

// ---- Kernel 3a: symmetric S -> E fp8 (packed), triangle grid, MX K=128 ----
__global__ __launch_bounds__(256) void k_s_sym(const unsigned char* __restrict__ xb,
                                               unsigned char* __restrict__ E,
                                               float* __restrict__ lsum) {
  __shared__ __align__(16) unsigned char As[8 * 128 * 16];  // 16 KB
  __shared__ __align__(16) unsigned char Bs[8 * 128 * 16];  // 16 KB
  const int tid = threadIdx.x;
  const int lane = tid & 63, w = tid >> 6;
  const int quad = lane >> 4, l15 = lane & 15;
  const int wi = w >> 1, wj = w & 1;

  const int idx = blockIdx.x;
  int bj = (int)((sqrtf(8.0f * idx + 1.0f) - 1.0f) * 0.5f);
  while ((bj + 1) * (bj + 2) / 2 <= idx) ++bj;
  while (bj * (bj + 1) / 2 > idx) --bj;
  const int bi = idx - bj * (bj + 1) / 2;
  const int it0 = bi * 128, jt0 = bj * 128;

  floatx4 acc[4][4];
#pragma unroll
  for (int a = 0; a < 4; ++a)
#pragma unroll
    for (int b = 0; b < 4; ++b) acc[a][b] = {0.f, 0.f, 0.f, 0.f};

  // packed staging: per iter 16 KB/side; wave w covers bytes [w*4K, w*4K+4K)
  const unsigned char* gA = xb + (size_t)bi * XTILE_B + w * 4096 + lane * 16;
  const unsigned char* gB = xb + (size_t)bj * XTILE_B + w * 4096 + lane * 16;
  unsigned char* lA = As + w * 4096;
  unsigned char* lB = Bs + w * 4096;

  for (int kk = 0; kk < 8; ++kk) {
#pragma unroll
    for (int q = 0; q < 4; ++q) {
      async16(lA + q * 1024, gA + q * 1024);
      async16(lB + q * 1024, gB + q * 1024);
    }
    gA += 16384; gB += 16384;
    __syncthreads();
    intx8 bf[4];
#pragma unroll
    for (int fn = 0; fn < 4; ++fn)
      bf[fn] = frag32(Bs, quad, wj * 64 + fn * 16 + l15);
#pragma unroll
    for (int fm = 0; fm < 4; ++fm) {
      const intx8 af = frag32(As, quad, wi * 64 + fm * 16 + l15);
#pragma unroll
      for (int fn = 0; fn < 4; ++fn)
        acc[fm][fn] = __builtin_amdgcn_mfma_scale_f32_16x16x128_f8f6f4(
            af, bf[fn], acc[fm][fn], 0, 0, 0, SCALE1, 0, SCALE1);
    }
    __syncthreads();
  }

  // P = exp(10*s - 10); s_raw = 256*s (x scaled by 16 each side)
#pragma unroll
  for (int fm = 0; fm < 4; ++fm)
#pragma unroll
    for (int fn = 0; fn < 4; ++fn)
#pragma unroll
      for (int reg = 0; reg < 4; ++reg) {
        float p = __expf(fmaf(acc[fm][fn][reg], 10.0f / 256.0f, -10.f));
        if (bi == bj &&
            (wi * 64 + fm * 16 + quad * 4 + reg) == (wj * 64 + fn * 16 + l15))
          p = 0.f;
        acc[fm][fn][reg] = p;
      }

  // normal-orientation packed stores + row sums
  unsigned char* Ei = E + (size_t)bi * PTILE_B;
#pragma unroll
  for (int fm = 0; fm < 4; ++fm)
#pragma unroll
    for (int reg = 0; reg < 4; ++reg) {
      const int row = wi * 64 + fm * 16 + quad * 4 + reg;
      float s = 0.f;
#pragma unroll
      for (int fn = 0; fn < 4; ++fn) {
        const float p = acc[fm][fn][reg];
        s += p;
        Ei[((jt0 >> 4) + wj * 4 + fn) * 2048 + row * 16 + l15] = f2f8(p * ESCALE);
      }
#pragma unroll
      for (int m = 1; m < 16; m <<= 1) s += __shfl_xor(s, m);
      if (l15 == 0) unsafeAtomicAdd(&lsum[it0 + row], s);
    }

  if (bi != bj) {  // transposed packed store + col sums
    unsigned char* Ej = E + (size_t)bj * PTILE_B;
#pragma unroll
    for (int fn = 0; fn < 4; ++fn) {
      const int col = wj * 64 + fn * 16 + l15;  // i-local row within tile bj
      float cs = 0.f;
#pragma unroll
      for (int fm = 0; fm < 4; ++fm) {
        int pk = __builtin_amdgcn_cvt_pk_fp8_f32(acc[fm][fn][0] * ESCALE,
                                                 acc[fm][fn][1] * ESCALE, 0, false);
        pk = __builtin_amdgcn_cvt_pk_fp8_f32(acc[fm][fn][2] * ESCALE,
                                             acc[fm][fn][3] * ESCALE, pk, true);
        cs += acc[fm][fn][0] + acc[fm][fn][1] + acc[fm][fn][2] + acc[fm][fn][3];
        *reinterpret_cast<int*>(
            &Ej[((it0 >> 4) + wi * 4 + fm) * 2048 + col * 16 + quad * 4]) = pk;
      }
      cs += __shfl_xor(cs, 16);
      cs += __shfl_xor(cs, 32);
      if (quad == 0) unsafeAtomicAdd(&lsum[jt0 + col], cs);
    }
  }
}

// ---------------- Kernel 3b: full-grid fallback (chunked, packed) ----------
__global__ __launch_bounds__(256) void k_s_full(const unsigned char* __restrict__ xb,
                                                unsigned char* __restrict__ E,
                                                float* __restrict__ lsum, int ch0) {
  __shared__ __align__(16) unsigned char As[8 * 128 * 16];
  __shared__ __align__(16) unsigned char Bs[8 * 128 * 16];
  const int tid = threadIdx.x;
  const int lane = tid & 63, w = tid >> 6;
  const int quad = lane >> 4, l15 = lane & 15;
  const int wi = w >> 1, wj = w & 1;
  const int bi = blockIdx.x;       // chunk-local i tile
  const int bj = blockIdx.y;       // global j tile
  const int it0 = bi * 128, jt0 = bj * 128;

  floatx4 acc[4][4];
#pragma unroll
  for (int a = 0; a < 4; ++a)
#pragma unroll
    for (int b = 0; b < 4; ++b) acc[a][b] = {0.f, 0.f, 0.f, 0.f};

  const unsigned char* gA =
      xb + (size_t)((ch0 >> 7) + bi) * XTILE_B + w * 4096 + lane * 16;
  const unsigned char* gB = xb + (size_t)bj * XTILE_B + w * 4096 + lane * 16;
  unsigned char* lA = As + w * 4096;
  unsigned char* lB = Bs + w * 4096;

  for (int kk = 0; kk < 8; ++kk) {
#pragma unroll
    for (int q = 0; q < 4; ++q) {
      async16(lA + q * 1024, gA + q * 1024);
      async16(lB + q * 1024, gB + q * 1024);
    }
    gA += 16384; gB += 16384;
    __syncthreads();
    intx8 bf[4];
#pragma unroll
    for (int fn = 0; fn < 4; ++fn)
      bf[fn] = frag32(Bs, quad, wj * 64 + fn * 16 + l15);
#pragma unroll
    for (int fm = 0; fm < 4; ++fm) {
      const intx8 af = frag32(As, quad, wi * 64 + fm * 16 + l15);
#pragma unroll
      for (int fn = 0; fn < 4; ++fn)
        acc[fm][fn] = __builtin_amdgcn_mfma_scale_f32_16x16x128_f8f6f4(
            af, bf[fn], acc[fm][fn], 0, 0, 0, SCALE1, 0, SCALE1);
    }
    __syncthreads();
  }

  unsigned char* Ei = E + (size_t)bi * PTILE_B;
#pragma unroll
  for (int fm = 0; fm < 4; ++fm)
#pragma unroll
    for (int reg = 0; reg < 4; ++reg) {
      const int row = wi * 64 + fm * 16 + quad * 4 + reg;
      float s = 0.f;
#pragma unroll
      for (int fn = 0; fn < 4; ++fn) {
        const int col = jt0 + wj * 64 + fn * 16 + l15;
        float p = __expf(fmaf(acc[fm][fn][reg], 10.0f / 256.0f, -10.f));
        if (ch0 + it0 + row == col) p = 0.f;
        s += p;
        Ei[(col >> 4) * 2048 + row * 16 + (col & 15)] = f2f8(p * ESCALE);
      }
#pragma unroll
      for (int m = 1; m < 16; m <<= 1) s += __shfl_xor(s, m);
      if (l15 == 0) unsafeAtomicAdd(&lsum[ch0 + it0 + row], s);
    }
}

// -------- Kernel 4: out^T = Vt8 @ E^T (MX fp8 K=128, packed operands) ------
__global__ __launch_bounds__(256, 2) void k_pv8(const unsigned char* __restrict__ E,
                                                const unsigned char* __restrict__ Vt8,
                                                const float* __restrict__ lsum,
                                                const float* __restrict__ emb,
                                                float* __restrict__ out,
                                                int swz, int ch0) {
  __shared__ __align__(16) unsigned char As[8 * 128 * 16];  // 16 KB
  __shared__ __align__(16) unsigned char Bs[8 * 128 * 16];  // 16 KB
  const int tid = threadIdx.x;
  const int lane = tid & 63, w = tid >> 6;
  const int quad = lane >> 4, l15 = lane & 15;
  const int wi = w >> 1, wj = w & 1;

  int dt, it;
  if (swz) {
    const int n = blockIdx.x;
    const int r = n & 7, q = n >> 3;
    dt = q >> 3; it = (q & 7) * 8 + r;
  } else {
    dt = blockIdx.x; it = blockIdx.y;
  }
  const int dt0 = dt * 128, it0 = it * 128;

  floatx4 acc[4][4];
#pragma unroll
  for (int a = 0; a < 4; ++a)
#pragma unroll
    for (int b = 0; b < 4; ++b) acc[a][b] = {0.f, 0.f, 0.f, 0.f};

  const unsigned char* gA = Vt8 + (size_t)dt * PTILE_B + w * 4096 + lane * 16;
  const unsigned char* gB = E + (size_t)it * PTILE_B + w * 4096 + lane * 16;
  unsigned char* lA = As + w * 4096;
  unsigned char* lB = Bs + w * 4096;

  for (int kk = 0; kk < 64; ++kk) {
#pragma unroll
    for (int q = 0; q < 4; ++q) {
      async16(lA + q * 1024, gA + q * 1024);
      async16(lB + q * 1024, gB + q * 1024);
    }
    gA += 16384; gB += 16384;
    __syncthreads();
    intx8 bf[4];
#pragma unroll
    for (int fn = 0; fn < 4; ++fn)
      bf[fn] = frag32(Bs, quad, wj * 64 + fn * 16 + l15);
#pragma unroll
    for (int fm = 0; fm < 4; ++fm) {
      const intx8 af = frag32(As, quad, wi * 64 + fm * 16 + l15);
#pragma unroll
      for (int fn = 0; fn < 4; ++fn)
        acc[fm][fn] = __builtin_amdgcn_mfma_scale_f32_16x16x128_f8f6f4(
            af, bf[fn], acc[fm][fn], 0, 0, 0, SCALE1, 0, SCALE1);
    }
    __syncthreads();
  }

#pragma unroll
  for (int fn = 0; fn < 4; ++fn) {
    const int i = it0 + wj * 64 + fn * 16 + l15;
    const float rinv = 1.0f / (1.0f + lsum[ch0 + i]);
#pragma unroll
    for (int fm = 0; fm < 4; ++fm) {
      const int d = dt0 + wi * 64 + fm * 16 + quad * 4;
      const float4 e = *reinterpret_cast<const float4*>(emb + (size_t)(ch0 + i) * NDIM + d);
      float4 o;
      o.x = (e.x + acc[fm][fn][0] * EINV) * rinv;
      o.y = (e.y + acc[fm][fn][1] * EINV) * rinv;
      o.z = (e.z + acc[fm][fn][2] * EINV) * rinv;
      o.w = (e.w + acc[fm][fn][3] * EINV) * rinv;
      *reinterpret_cast<float4*>(out + (size_t)(ch0 + i) * NDIM + d) = o;
    }
  }
}

extern "C" void kernel_launch(void* const* d_in, const int* in_sizes, int n_in,
                              void* d_out, int out_size, void* d_ws, size_t ws_size,
                              hipStream_t stream) {
  const float* emb = (const float*)d_in[0];
  float* out = (float*)d_out;

  unsigned char* xb = (unsigned char*)d_ws;                            // 8 MB packed fp8
  unsigned char* Vt8 = (unsigned char*)((char*)d_ws + (8ull << 20));   // 8 MB packed fp8
  float* lsum = (float*)((char*)d_ws + (16ull << 20));                 // 32 KB
  unsigned char* E = (unsigned char*)((char*)d_ws + (17ull << 20));    // 64 MB packed fp8

  const size_t avail = ws_size > (17ull << 20) ? ws_size - (17ull << 20) : 0;
  int nc = 1;
  while (nc < 64 && ((size_t)(NROWS / nc) * NROWS) > avail) nc <<= 1;
  const int RC = NROWS / nc;

  hipMemsetAsync(lsum, 0, NROWS * sizeof(float), stream);
  k_norm<<<NROWS, 256, 0, stream>>>(emb, xb);
  k_tr8<<<dim3(NROWS / 64, NDIM / 64), 256, 0, stream>>>(emb, Vt8);

  if (nc == 1) {
    const int nt = NROWS / 128;
    k_s_sym<<<nt * (nt + 1) / 2, 256, 0, stream>>>(xb, E, lsum);
    k_pv8<<<512, 256, 0, stream>>>(E, Vt8, lsum, emb, out, 1, 0);
  } else {
    for (int c = 0; c < nc; ++c) {
      const int ch0 = c * RC;
      k_s_full<<<dim3(RC / 128, NROWS / 128), 256, 0, stream>>>(xb, E, lsum, ch0);
      k_pv8<<<dim3(NDIM / 128, RC / 128), 256, 0, stream>>>(E, Vt8, lsum, emb, out, 0, ch0);
    }
  }
}